// Round 6
// baseline (395.273 us; speedup 1.0000x reference)
//
#include <hip/hip_runtime.h>
#include <hip/hip_bf16.h>
#include <stdint.h>

// QKV projection: C[M,N] = A[M,K] * W[N,K]^T + bias[N]
// M=16384, N=3072, K=1024, fp32 in/out, graded at bf16 tolerance.
// Stage 1: fused fp32->bf16 convert of A and W into d_ws (unchanged).
// Stage 2 (v7): v6's counted-vmcnt pipeline with the CROSS-WAVE RACE FIXED.
// Invariant: vmcnt is PER-WAVE, but LDS tiles are staged cooperatively, so
// a stage group G read in phase p must be retired by every wave's own
// vm-wait BEFORE a barrier preceding p. v6 waited at the top of the reading
// phase (after the barrier) -> other waves' loads could still be in flight.
// v7 places all waits at phase end, pre-barrier, with re-derived counts.
//
// Wave map (unchanged from v6): wave (wm,wn) owns C rows
// {wm*64..+63} u {128+wm*64..+63} x cols {wn*32..+31} u {128+wn*32..+31}:
//   aA = A.h0 (rows 0-127), aB = A.h1, bA = B.h0, bB = B.h1
// Per-tile schedule (tile t reads buf X=(t&1); stages t+2 INTO X; group
// G(t,i) = loads issued at tile t phase i; sizes p1=4, p2=2, p3=2):
//   ph1: rd bB(X.B.h1) | stg p1: A.h0+B.h0(t+2)->X | Q00(aA,bA) | lgkm0 VM1 bar
//   ph2: rd aB(X.A.h1) | stg p2: B.h1(t+2)->X      | Q02(aA,bB) | lgkm0 VM2 bar
//   ph3: rd aA'(Y.A.h0)| stg p3: A.h1(t+2)->X      | Q40(aB,bA) | lgkm0 VM3 bar
//   ph4: rd bA'(Y.B.h0)|                           | Q42(aB,bB) | lgkm0 bar
// Steady-state bookkeeping (per wave, S = outstanding at wait point):
//   ph1 start S=10 {G(t-2,3)2, G(t-1,1)4, G(t-1,2)2, G(t-1,3)2}; +p1 -> 14;
//     VM1=12 retires G(t-2,3)  [reader: t ph2's aB]       -> S=12
//   ph2: +p2 -> 14; VM2=10 retires G(t-1,1) [readers: t ph3 aA', t ph4 bA']
//     -> S=10
//   ph3: +p3 -> 12; VM3=10 retires G(t-1,2) [reader: t+1 ph1's bB] -> S=10
//   ph4: no stage, no wait -> S=10 = ph1-start invariant (induction holds).
//   Reader checks: t ph1's bB needs G(t-2,2), retired at t-1 ph3 VM3 (one
//   barrier earlier than required). Every group gets >=5 phases (~2000 cyc
//   > 900-cyc HBM latency) of flight; >=10 loads always outstanding (T4).
// Tail (no staging => fixed counts would become no-ops, so custom):
//   t14: VM=(8,4,2)  retires G(12,3) / G(13,1) / G(13,2) exactly.
//   t15: VM=(0,-,-)  retires G(13,3); ph3/ph4 do dead prefetches.
// WAR: every staged region's last reader is lgkm0'd >=1 barrier earlier
// (X.A.h0: t-1 ph3; X.B.h0: t-1 ph4; X.B.h1: t ph1; X.A.h1: t ph2).
// K-accumulation order per C element unchanged -> absmax 0.03125.

typedef __attribute__((ext_vector_type(8))) short short8;            // 8 x bf16
typedef __attribute__((ext_vector_type(8))) unsigned short ushort8;  // 8 x bf16 bits
typedef __attribute__((ext_vector_type(4))) float f32x4;

#define MTOT 16384
#define NTOT 3072
#define KTOT 1024
#define BUFS 65536     // one buffer: A region 32K + B region 32K
#define BREG 32768     // B region offset inside a buffer
#define HREG 16384     // half-region offset (128 rows x 128 B)

#define WS_A_OFF   0u
#define WS_A_BYTES (MTOT * KTOT * 2u)
#define WS_W_OFF   (WS_A_OFF + WS_A_BYTES)

#define WAIT_LGKM0 asm volatile("s_waitcnt lgkmcnt(0)" ::: "memory")
#define BARRIER    __builtin_amdgcn_s_barrier()

// ---- fused fp32->bf16 convert for A and W (unchanged) -------------------
__global__ __launch_bounds__(256) void cvt_aw(
    const float* __restrict__ A, const float* __restrict__ W,
    unsigned short* __restrict__ dA, unsigned short* __restrict__ dW)
{
    const float* src;
    unsigned short* dst;
    long i;
    if (blockIdx.x < 8192) {
        src = A; dst = dA;
        i = ((long)blockIdx.x * 256 + threadIdx.x) * 8;
    } else {
        src = W; dst = dW;
        i = ((long)(blockIdx.x - 8192) * 256 + threadIdx.x) * 8;
    }
    f32x4 a = *(const f32x4*)(src + i);
    f32x4 b = *(const f32x4*)(src + i + 4);
    ushort8 r;
    r[0] = __bfloat16_as_ushort(__float2bfloat16(a[0]));
    r[1] = __bfloat16_as_ushort(__float2bfloat16(a[1]));
    r[2] = __bfloat16_as_ushort(__float2bfloat16(a[2]));
    r[3] = __bfloat16_as_ushort(__float2bfloat16(a[3]));
    r[4] = __bfloat16_as_ushort(__float2bfloat16(b[0]));
    r[5] = __bfloat16_as_ushort(__float2bfloat16(b[1]));
    r[6] = __bfloat16_as_ushort(__float2bfloat16(b[2]));
    r[7] = __bfloat16_as_ushort(__float2bfloat16(b[3]));
    *(ushort8*)(dst + i) = r;
}

__device__ __forceinline__ void gload_lds16(const void* g, void* l) {
    __builtin_amdgcn_global_load_lds(
        (const __attribute__((address_space(1))) void*)g,
        (__attribute__((address_space(3))) void*)l,
        16, 0, 0);
}

// counted vmcnt wait, pre-barrier; N = -1 skips.
template<int N>
__device__ __forceinline__ void wait_vm() {
    if constexpr (N == 12)      asm volatile("s_waitcnt vmcnt(12)" ::: "memory");
    else if constexpr (N == 10) asm volatile("s_waitcnt vmcnt(10)" ::: "memory");
    else if constexpr (N == 8)  asm volatile("s_waitcnt vmcnt(8)"  ::: "memory");
    else if constexpr (N == 4)  asm volatile("s_waitcnt vmcnt(4)"  ::: "memory");
    else if constexpr (N == 2)  asm volatile("s_waitcnt vmcnt(2)"  ::: "memory");
    else if constexpr (N == 0)  asm volatile("s_waitcnt vmcnt(0)"  ::: "memory");
}

// stage one HALF operand tile (128 rows x 64 cols bf16 = 16 KB, 2 loads;
// wave w writes rows w*8..w*8+7 of each 64-row quarter; source column
// pre-inverse-swizzled per rule #21)
__device__ __forceinline__ void stage2(const unsigned short* g, char* l) {
    gload_lds16(g,         l);
    gload_lds16(g + 65536, l + 8192);   // +64 rows
}

// fragment loads (swizzled chunk addressing; ch0^64 = k-slice 1)
__device__ __forceinline__ void rd_a4(short8 (&d)[4][2], const char* base, int ch0) {
    const int c1 = ch0 ^ 64;
    #pragma unroll
    for (int i = 0; i < 4; ++i) {
        d[i][0] = *(const short8*)(base + i * 2048 + ch0);
        d[i][1] = *(const short8*)(base + i * 2048 + c1);
    }
}
__device__ __forceinline__ void rd_b2(short8 (&d)[2][2], const char* base, int ch0) {
    const int c1 = ch0 ^ 64;
    #pragma unroll
    for (int j = 0; j < 2; ++j) {
        d[j][0] = *(const short8*)(base + j * 2048 + ch0);
        d[j][1] = *(const short8*)(base + j * 2048 + c1);
    }
}

// one C-quadrant: 4(M) x 2(N) fragments x 2 k-slices = 16 MFMAs
template<int IO, int JO>
__device__ __forceinline__ void quad(f32x4 (&acc)[8][4],
                                     const short8 (&a)[4][2],
                                     const short8 (&b)[2][2])
{
    __builtin_amdgcn_s_setprio(1);
    #pragma unroll
    for (int i = 0; i < 4; ++i) {
        #pragma unroll
        for (int j = 0; j < 2; ++j) {
            f32x4 c = acc[IO + i][JO + j];
            c = __builtin_amdgcn_mfma_f32_16x16x32_bf16(a[i][0], b[j][0], c, 0, 0, 0);
            c = __builtin_amdgcn_mfma_f32_16x16x32_bf16(a[i][1], b[j][1], c, 0, 0, 0);
            acc[IO + i][JO + j] = c;
        }
    }
    __builtin_amdgcn_s_setprio(0);
}

// one K-tile; XOFF = this tile's buffer (compile-time). ke2 = element
// column offset of tile t+2 (staged into THIS buffer when STG).
// V1/V2/V3 = pre-barrier vmcnt immediates at ends of ph1/ph2/ph3.
template<int XOFF, int V1, int V2, int V3, bool STG>
__device__ __forceinline__ void ktile(
    char* sm, const unsigned short* gA, const unsigned short* gB, int ke2,
    int ra, int rb, int ch0, int w,
    short8 (&aA)[4][2], short8 (&aB)[4][2],
    short8 (&bA)[2][2], short8 (&bB)[2][2],
    f32x4 (&acc)[8][4])
{
    constexpr int YOFF = XOFF ^ BUFS;
    const char* AX = sm + XOFF + ra;
    const char* BX = sm + XOFF + BREG + rb;
    const char* AY = sm + YOFF + ra;
    const char* BY = sm + YOFF + BREG + rb;
    char* stA = sm + XOFF + w * 1024;
    char* stB = sm + XOFF + BREG + w * 1024;

    // ph1: bB from X.B.h1 | stage p1: A.h0+B.h0 (t+2) | Q00(aA,bA)
    rd_b2(bB, BX + HREG, ch0);
    if (STG) { stage2(gA + ke2, stA); stage2(gB + ke2, stB); }
    quad<0, 0>(acc, aA, bA);
    WAIT_LGKM0; wait_vm<V1>(); BARRIER;

    // ph2: aB from X.A.h1 | stage p2: B.h1 (t+2) | Q02(aA,bB)
    rd_a4(aB, AX + HREG, ch0);
    if (STG) stage2(gB + ke2 + 131072, stB + HREG);
    quad<0, 2>(acc, aA, bB);
    WAIT_LGKM0; wait_vm<V2>(); BARRIER;

    // ph3: next tile's aA from Y.A.h0 | stage p3: A.h1 (t+2) | Q40(aB,bA)
    rd_a4(aA, AY, ch0);
    if (STG) stage2(gA + ke2 + 131072, stA + HREG);
    quad<4, 0>(acc, aB, bA);
    WAIT_LGKM0; wait_vm<V3>(); BARRIER;

    // ph4: next tile's bA from Y.B.h0 | Q42(aB,bB)
    rd_b2(bA, BY, ch0);
    quad<4, 2>(acc, aB, bB);
    WAIT_LGKM0; BARRIER;
}

__global__ __launch_bounds__(512, 2) void qkv_gemm_8ph(
    const unsigned short* __restrict__ A,   // [M,K] bf16 bits (ws)
    const unsigned short* __restrict__ W,   // [N,K] bf16 bits (ws)
    const float* __restrict__ bias,         // [N] f32
    float* __restrict__ C)                  // [M,N] f32
{
    __shared__ __align__(16) char sm[2 * BUFS];   // 128 KiB

    const int t    = threadIdx.x;
    const int l    = t & 63;
    const int w    = t >> 6;
    const int fr   = l & 15;
    const int qd   = l >> 4;

    // T1: XCD-bijective swizzle; 768 blocks = 8 XCDs x 96 (96 = 8 A-panels).
    const int bid = blockIdx.x;
    const int idx = (bid & 7) * 96 + (bid >> 3);
    const int mt = idx / 12, nt = idx % 12;
    const int m0 = mt * 256, n0 = nt * 256;

    const int wm = w >> 2, wn = w & 3;     // 2 M-warps x 4 N-warps
    // wave sub-tile bases: rows wm*64 (+128 for aB), cols wn*32 (+128 for bB)
    const int arow = wm * 64, bcol = wn * 32;

    // staging source: inverse-XOR-swizzled column (rule #21)
    const int srow = w * 8 + (l >> 3);
    const int schk = ((l & 7) ^ (l >> 3)) << 3;
    const unsigned short* gA = A + (size_t)(m0 + srow) * KTOT + schk;
    const unsigned short* gB = W + (size_t)(n0 + srow) * KTOT + schk;

    // LDS read addressing: phys chunk = logical chunk ^ (row&7); row&7==fr&7
    const int ra  = (arow + fr) * 128;
    const int rb  = (bcol + fr) * 128;
    const int ch0 = (qd ^ (fr & 7)) << 4;

    f32x4 acc[8][4];
    #pragma unroll
    for (int i = 0; i < 8; ++i)
        #pragma unroll
        for (int j = 0; j < 4; ++j)
            acc[i][j] = (f32x4){0.f, 0.f, 0.f, 0.f};

    short8 aA[4][2], aB[4][2], bA[2][2], bB[2][2];

    // prologue: stage t0 -> buf0 and t1 -> buf1 in steady-state group order
    // (p1: Ah0+Bh0, p2: Bh1, p3: Ah1 per tile); vmcnt(8) PRE-BARRIER drains
    // all of t0 for every wave (cross-wave safe), leaving t1's 8 in flight
    // as groups G(-1,1)=4, G(-1,2)=2, G(-1,3)=2; then pre-read t0's aA,bA.
    {
        char* sA0 = sm + w * 1024;
        char* sB0 = sm + BREG + w * 1024;
        stage2(gA,               sA0);               // t0 A.h0
        stage2(gB,               sB0);               // t0 B.h0
        stage2(gB + 131072,      sB0 + HREG);        // t0 B.h1
        stage2(gA + 131072,      sA0 + HREG);        // t0 A.h1
        stage2(gA + 64,          sA0 + BUFS);        // t1 A.h0  G(-1,1)
        stage2(gB + 64,          sB0 + BUFS);        // t1 B.h0  G(-1,1)
        stage2(gB + 64 + 131072, sB0 + BUFS + HREG); // t1 B.h1  G(-1,2)
        stage2(gA + 64 + 131072, sA0 + BUFS + HREG); // t1 A.h1  G(-1,3)
        wait_vm<8>();
        BARRIER;
        rd_a4(aA, sm + ra,        ch0);
        rd_b2(bA, sm + BREG + rb, ch0);
    }

    #pragma unroll 1
    for (int p = 0; p < 7; ++p) {          // tiles 0..13, staging tiles 2..15
        ktile<0,    12, 10, 10, true>(sm, gA, gB, (2 * p + 2) * 64,
                                      ra, rb, ch0, w, aA, aB, bA, bB, acc);
        ktile<BUFS, 12, 10, 10, true>(sm, gA, gB, (2 * p + 3) * 64,
                                      ra, rb, ch0, w, aA, aB, bA, bB, acc);
    }
    // t14: no staging; custom counts retire G(12,3)/G(13,1)/G(13,2).
    ktile<0,    8, 4, 2, false>(sm, gA, gB, 0, ra, rb, ch0, w,
                                aA, aB, bA, bB, acc);
    // t15: retire G(13,3) at ph1-end; ph3/ph4 are dead prefetches.
    ktile<BUFS, 0, -1, -1, false>(sm, gA, gB, 0, ra, rb, ch0, w,
                                  aA, aB, bA, bB, acc);

    // epilogue: C/D layout col=lane&15, row=quad*4+reg (m89-verified),
    // with the sub-tile remap (i>=4 -> +128 rows; j>=2 -> +128 cols).
    float bv[4];
    #pragma unroll
    for (int j = 0; j < 4; ++j) {
        const int cb = (j < 2) ? (bcol + j * 16) : (128 + bcol + (j - 2) * 16);
        bv[j] = bias[n0 + cb + fr];
    }

    #pragma unroll
    for (int i = 0; i < 8; ++i) {
        const int rbase = (i < 4) ? (arow + i * 16) : (128 + arow + (i - 4) * 16);
        const int row = m0 + rbase + qd * 4;
        #pragma unroll
        for (int j = 0; j < 4; ++j) {
            const int cb = (j < 2) ? (bcol + j * 16) : (128 + bcol + (j - 2) * 16);
            float* pp = C + (size_t)row * NTOT + (n0 + cb + fr);
            #pragma unroll
            for (int r = 0; r < 4; ++r)
                pp[(size_t)r * NTOT] = acc[i][j][r] + bv[j];
        }
    }
}

extern "C" void kernel_launch(void* const* d_in, const int* in_sizes, int n_in,
                              void* d_out, int out_size, void* d_ws, size_t ws_size,
                              hipStream_t stream) {
    const float* q  = (const float*)d_in[0];
    const float* Wq = (const float*)d_in[1];
    const float* bq = (const float*)d_in[2];
    float*       C  = (float*)d_out;

    char* ws = (char*)d_ws;
    unsigned short* wsA = (unsigned short*)(ws + WS_A_OFF);
    unsigned short* wsW = (unsigned short*)(ws + WS_W_OFF);

    cvt_aw<<<8192 + 1536, 256, 0, stream>>>(q, Wq, wsA, wsW);

    qkv_gemm_8ph<<<dim3(768), dim3(512), 0, stream>>>(wsA, wsW, bq, C);
}